// Round 3
// baseline (408.436 us; speedup 1.0000x reference)
//
#include <hip/hip_runtime.h>

// StandardTrafficCoordinator: B=1024, N=64, F=512, H=512.
// pre = 63*(states@W1^T + bg) + (Am@states)@W2f^T + msg_d@W2d^T
//     = states@(63*W1)^T + Am@(states@W2f^T) + msg_d@W2d^T   (associativity)
// One block per batch; all GEMMs bf16 MFMA 16x16x32 in swapped orientation D[h][i].

typedef __attribute__((ext_vector_type(8))) short bf16x8;
typedef __attribute__((ext_vector_type(4))) float f32x4;
typedef __attribute__((ext_vector_type(4))) unsigned short us4;

__device__ __forceinline__ unsigned short f2bf(float x) {
  union { float f; unsigned int u; } c; c.f = x;
  return (unsigned short)((c.u + 0x7FFFu + ((c.u >> 16) & 1u)) >> 16);  // RNE
}

// Pre-kernel: Wgb[h][k] = bf16((k<512?63:1)*Wg[h][k]), k in [0,1024).
// auxw[h][8] = {63*bg[h], W2d0[h], W2d1[h], W4[0][h], W4[1][h], W5[0][h], 0, 0}
__global__ void prep_kernel(const float* __restrict__ Wg, const float* __restrict__ bg,
                            const float* __restrict__ W4, const float* __restrict__ W5,
                            unsigned short* __restrict__ Wgb, float* __restrict__ auxw)
{
  const int h = blockIdx.x;
  const int t = threadIdx.x;
  const float* row = Wg + h * 1026;
  const int k0 = t * 4;
#pragma unroll
  for (int q = 0; q < 4; ++q) {
    int k = k0 + q;
    float s = (k < 512) ? 63.0f : 1.0f;
    Wgb[h * 1024 + k] = f2bf(s * row[k]);
  }
  if (t == 0) {
    float* a = auxw + h * 8;
    a[0] = 63.0f * bg[h];
    a[1] = row[1024];
    a[2] = row[1025];
    a[3] = W4[h];
    a[4] = W4[512 + h];
    a[5] = W5[h];
    a[6] = 0.0f; a[7] = 0.0f;
  }
}

__global__ __launch_bounds__(256, 1) void traffic_kernel(
    const float* __restrict__ locs, const float* __restrict__ states,
    const unsigned short* __restrict__ Wgb, const float* __restrict__ auxw,
    const float* __restrict__ b4, const float* __restrict__ b5,
    float* __restrict__ out)
{
  __shared__ unsigned short S[64 * 520];     // states bf16, row-major, +8 pad (66.5 KB)
  __shared__ unsigned short U2T[512 * 72];   // wave-private [128][72] slices (73.7 KB)
  __shared__ unsigned short Am[64 * 72];     // row-normalized adjacency, diag 0 (9.2 KB)
  __shared__ float locs_s[128];
  __shared__ float msgd[128];                // [64][2]
  __shared__ float red[4 * 64 * 3];          // cross-wave epilogue partials

  const int t = threadIdx.x;
  const int b = blockIdx.x;
  const int lane = t & 63;
  const int w = t >> 6;
  const int llo = lane & 15;
  const int lhi = lane >> 4;

  if (t < 128) locs_s[t] = locs[b * 128 + t];
  __syncthreads();

  // ---- Phase A: adjacency Am + msg_d (thread = (row i, 16-col strip)) ----
  {
    const int i = t >> 2;
    const int j0 = (t & 3) * 16;
    const float xi = locs_s[2*i], yi = locs_s[2*i+1];
    float a[16]; float psum = 0.f;
#pragma unroll
    for (int q = 0; q < 16; ++q) {
      int j = j0 + q;
      float dx = xi - locs_s[2*j];
      float dy = yi - locs_s[2*j+1];
      a[q] = (dx*dx + dy*dy < 1.0f) ? 1.0f : 0.0f;   // norm<1 <=> dist2<1
      psum += a[q];
    }
    psum += __shfl_xor(psum, 1);
    psum += __shfl_xor(psum, 2);                      // row degree incl. self
    const float inv = 1.0f / psum;
    float m0 = 0.f, m1 = 0.f;
#pragma unroll
    for (int q = 0; q < 16; ++q) {
      int j = j0 + q;
      float v = (j == i) ? 0.f : a[q] * inv;          // zero diagonal AFTER normalize
      a[q] = v;
      m0 += v * (xi - locs_s[2*j]);
      m1 += v * (yi - locs_s[2*j+1]);
    }
    m0 += __shfl_xor(m0, 1); m0 += __shfl_xor(m0, 2);
    m1 += __shfl_xor(m1, 1); m1 += __shfl_xor(m1, 2);
    if ((t & 3) == 0) { msgd[2*i] = m0; msgd[2*i+1] = m1; }
    union { unsigned short h8[8]; uint4 v4; } pk;
#pragma unroll
    for (int q = 0; q < 8; ++q) pk.h8[q] = f2bf(a[q]);
    *(uint4*)&Am[i*72 + j0] = pk.v4;
#pragma unroll
    for (int q = 0; q < 8; ++q) pk.h8[q] = f2bf(a[8+q]);
    *(uint4*)&Am[i*72 + j0 + 8] = pk.v4;
  }

  // ---- Phase B: states f32 -> S bf16 (coalesced float4 loads) ----
  {
    const float4* sb = (const float4*)(states + (size_t)b * 32768);
#pragma unroll
    for (int it = 0; it < 32; ++it) {
      int id = it * 256 + t;
      int j = id >> 7;
      int f0 = (id & 127) * 4;
      float4 v = sb[id];
      us4 s4;
      s4.x = f2bf(v.x); s4.y = f2bf(v.y);
      s4.z = f2bf(v.z); s4.w = f2bf(v.w);
      *(us4*)&S[j * 520 + f0] = s4;
    }
  }
  __syncthreads();

  const int hw = w * 128;                    // wave's h-slice
  unsigned short* U2w = &U2T[w * 128 * 72];  // wave-private

  f32x4 acc[8][4];                           // [mt(h)][nt(i)]

  auto zero_acc = [&]() {
#pragma unroll
    for (int mt = 0; mt < 8; ++mt)
#pragma unroll
      for (int nt = 0; nt < 4; ++nt)
        acc[mt][nt] = f32x4{0.f, 0.f, 0.f, 0.f};
  };

  // one K-step (K=32): A-frag = Wgb rows (global bf16), B-frag = S rows (LDS)
  auto gemm_step = [&](int kg, int kl) {
    bf16x8 afr[8], bfr[4];
#pragma unroll
    for (int mt = 0; mt < 8; ++mt)
      afr[mt] = *(const bf16x8*)&Wgb[(size_t)(hw + mt*16 + llo) * 1024 + kg + lhi*8];
#pragma unroll
    for (int nt = 0; nt < 4; ++nt)
      bfr[nt] = *(const bf16x8*)&S[(nt*16 + llo) * 520 + kl + lhi*8];
#pragma unroll
    for (int mt = 0; mt < 8; ++mt)
#pragma unroll
      for (int nt = 0; nt < 4; ++nt)
        acc[mt][nt] = __builtin_amdgcn_mfma_f32_16x16x32_bf16(afr[mt], bfr[nt], acc[mt][nt], 0, 0, 0);
  };

  // ---- C1: U2[h][j] = sum_f W2f[h][f]*states[j][f]  (Wgb cols 512..1023) ----
  zero_acc();
#pragma unroll 2
  for (int ks = 0; ks < 16; ++ks) gemm_step(512 + ks*32, ks*32);

  // write U2T slice (wave-private; same-wave RAW handled by in-order DS pipe)
#pragma unroll
  for (int mt = 0; mt < 8; ++mt)
#pragma unroll
    for (int nt = 0; nt < 4; ++nt)
#pragma unroll
      for (int r = 0; r < 4; ++r)
        U2w[(mt*16 + lhi*4 + r) * 72 + nt*16 + llo] = f2bf(acc[mt][nt][r]);

  // ---- C2: preT[h][i] = sum_f 63*W1[h][f]*states[i][f]  (cols 0..511, 63 folded) ----
  zero_acc();
#pragma unroll 2
  for (int ks = 0; ks < 16; ++ks) gemm_step(ks*32, ks*32);

  // ---- D': preT[h][i] += sum_j U2T[h][j] * Am[i][j]  (K=64) ----
#pragma unroll
  for (int ks = 0; ks < 2; ++ks) {
    bf16x8 afr[8], bfr[4];
#pragma unroll
    for (int mt = 0; mt < 8; ++mt)
      afr[mt] = *(const bf16x8*)&U2w[(mt*16 + llo) * 72 + ks*32 + lhi*8];
#pragma unroll
    for (int nt = 0; nt < 4; ++nt)
      bfr[nt] = *(const bf16x8*)&Am[(nt*16 + llo) * 72 + ks*32 + lhi*8];
#pragma unroll
    for (int mt = 0; mt < 8; ++mt)
#pragma unroll
      for (int nt = 0; nt < 4; ++nt)
        acc[mt][nt] = __builtin_amdgcn_mfma_f32_16x16x32_bf16(afr[mt], bfr[nt], acc[mt][nt], 0, 0, 0);
  }

  // ---- E: epilogue — + msg_d@W2d + 63*bg, relu, project to policies/values ----
  float mdx[4], mdy[4];
#pragma unroll
  for (int nt = 0; nt < 4; ++nt) {
    mdx[nt] = msgd[2*(nt*16 + llo)];
    mdy[nt] = msgd[2*(nt*16 + llo) + 1];
  }
  float pp0[4] = {0,0,0,0}, pp1[4] = {0,0,0,0}, vv[4] = {0,0,0,0};
#pragma unroll
  for (int mt = 0; mt < 8; ++mt) {
#pragma unroll
    for (int r = 0; r < 4; ++r) {
      int hh = hw + mt*16 + lhi*4 + r;
      float4 ax0 = *(const float4*)&auxw[hh*8];      // {63bg, W2d0, W2d1, W4_0}
      float4 ax1 = *(const float4*)&auxw[hh*8 + 4];  // {W4_1, W5, 0, 0}
#pragma unroll
      for (int nt = 0; nt < 4; ++nt) {
        float val = acc[mt][nt][r] + ax0.x + mdx[nt]*ax0.y + mdy[nt]*ax0.z;
        val = fmaxf(val, 0.f);
        pp0[nt] += val * ax0.w;
        pp1[nt] += val * ax1.x;
        vv[nt]  += val * ax1.y;
      }
    }
  }
#pragma unroll
  for (int nt = 0; nt < 4; ++nt) {   // reduce over the 4 lhi groups (h within wave)
    pp0[nt] += __shfl_xor(pp0[nt], 16); pp0[nt] += __shfl_xor(pp0[nt], 32);
    pp1[nt] += __shfl_xor(pp1[nt], 16); pp1[nt] += __shfl_xor(pp1[nt], 32);
    vv[nt]  += __shfl_xor(vv[nt], 16);  vv[nt]  += __shfl_xor(vv[nt], 32);
  }
  if (lane < 16) {
#pragma unroll
    for (int nt = 0; nt < 4; ++nt) {
      int i = nt*16 + llo;
      red[(w*64 + i)*3 + 0] = pp0[nt];
      red[(w*64 + i)*3 + 1] = pp1[nt];
      red[(w*64 + i)*3 + 2] = vv[nt];
    }
  }
  __syncthreads();
  if (t < 192) {                     // cross-wave reduce + bias + store
    int o = t >> 6;                  // 0,1 -> policies; 2 -> values
    int i = t & 63;
    float s = red[(0*64+i)*3+o] + red[(1*64+i)*3+o]
            + red[(2*64+i)*3+o] + red[(3*64+i)*3+o];
    s += (o < 2) ? b4[o] : b5[0];
    if (o < 2) out[((size_t)b*64 + i)*2 + o] = s;
    else       out[(size_t)131072 + (size_t)b*64 + i] = s;
  }
}

extern "C" void kernel_launch(void* const* d_in, const int* in_sizes, int n_in,
                              void* d_out, int out_size, void* d_ws, size_t ws_size,
                              hipStream_t stream)
{
  const float* locs   = (const float*)d_in[0];
  const float* states = (const float*)d_in[1];
  const float* Wg     = (const float*)d_in[2];
  const float* bg     = (const float*)d_in[3];
  const float* W4     = (const float*)d_in[4];
  const float* b4     = (const float*)d_in[5];
  const float* W5     = (const float*)d_in[6];
  const float* b5     = (const float*)d_in[7];

  unsigned short* Wgb = (unsigned short*)d_ws;                   // 1 MB bf16 weights
  float* auxw = (float*)((char*)d_ws + 512 * 1024 * 2);          // 16 KB epilogue table

  prep_kernel<<<512, 256, 0, stream>>>(Wg, bg, W4, W5, Wgb, auxw);
  traffic_kernel<<<1024, 256, 0, stream>>>(locs, states, Wgb, auxw, b4, b5, (float*)d_out);
}